// Round 21
// baseline (145.058 us; speedup 1.0000x reference)
//
#include <hip/hip_runtime.h>
#include <hip/hip_bf16.h>

#define B_N 8192
#define C_DIM 512
#define NT 64            // 128-wide tiles per dimension (fallback path)
#define NTRI 2080
#define NT2 32           // 256-wide tiles per dimension
#define NTRI2 528        // NT2*(NT2+1)/2
#define TGKEY 0xBDC0u    // negkey(bf16 0.09375): conservative top-64 pre-threshold

typedef __attribute__((ext_vector_type(4))) float f32x4;
typedef __attribute__((ext_vector_type(4))) int i32x4;
typedef __attribute__((address_space(3))) unsigned int lds_u32;
typedef const __attribute__((address_space(1))) unsigned int glb_u32;

__device__ __forceinline__ void gl_lds16b(const unsigned char* g, unsigned char* l) {
    __builtin_amdgcn_global_load_lds((glb_u32*)g, (lds_u32*)l, 16, 0, 0);
}

__device__ __forceinline__ unsigned short f2bf(float f) {
    unsigned int u = __float_as_uint(f);
    u += 0x7FFFu + ((u >> 16) & 1u);          // RNE
    return (unsigned short)(u >> 16);
}
__device__ __forceinline__ float bf2f(unsigned int s) {
    return __uint_as_float(s << 16);
}
// order-preserving key: float order -> unsigned ascending. key 0 impossible for finite sims.
__device__ __forceinline__ unsigned negkey(unsigned ub) {
    return (ub & 0x8000u) ? ((~ub) & 0xFFFFu) : (ub | 0x8000u);
}
__device__ __forceinline__ unsigned unkey(unsigned k) {
    return (k & 0x8000u) ? (k ^ 0x8000u) : ((~k) & 0xFFFFu);
}

// ---- one-block prep: layout detect, class bytes, class member lists (counting sort) ----
__global__ void prep_all(const unsigned int* __restrict__ t, unsigned char* __restrict__ tgb,
                         unsigned short* __restrict__ clist, int* __restrict__ off) {
    __shared__ int bad, cnt[128], base[128];
    const int tid = threadIdx.x;
    if (tid == 0) bad = 0;
    if (tid < 128) cnt[tid] = 0;
    __syncthreads();
    int local = 0;
    for (int k = tid; k < 4096; k += 256)        // first 32KB only: safe for both layouts
        if (t[2 * k + 1] != 0u) local = 1;
    if (local) atomicOr(&bad, 1);
    __syncthreads();
    const int is64 = (bad == 0);
    for (int i = 0; i < 32; ++i) {
        int j = i * 256 + tid;
        unsigned c = (is64 ? t[2 * j] : t[j]) & 127u;   // classes < 100
        tgb[j] = (unsigned char)c;
        atomicAdd(&cnt[c], 1);
    }
    __syncthreads();
    if (tid == 0) {
        int s = 0;
        for (int c = 0; c < 128; ++c) { base[c] = s; off[c] = s; s += cnt[c]; }
        off[128] = s;
    }
    __syncthreads();
    for (int i = 0; i < 32; ++i) {
        int j = i * 256 + tid;
        unsigned c = (is64 ? t[2 * j] : t[j]) & 127u;
        int idx = atomicAdd(&base[c], 1);
        clist[idx] = (unsigned short)j;
    }
}

// ---- per-class membership words: cm2[c*256+t] bit (q*8+e) = (tgb[q*2048+t*8+e]==c) ----
__global__ void class_masks(const unsigned char* __restrict__ tgb,
                            unsigned int* __restrict__ cm2) {
    const int c = blockIdx.x, t = threadIdx.x;
    unsigned w = 0;
#pragma unroll
    for (int q = 0; q < 4; ++q) {
        const unsigned char* base = tgb + q * 2048 + t * 8;
        unsigned b = 0;
#pragma unroll
        for (int e = 0; e < 8; ++e)
            b |= ((unsigned)(base[e] == c)) << e;
        w |= b << (8 * q);
    }
    cm2[c * 256 + t] = w;
}

// ---- L2 normalize rows, emit OCP e4m3 fp8 ----
__global__ __launch_bounds__(256) void normalize_k(const float* __restrict__ x,
                                                   unsigned char* __restrict__ nf8) {
    const int wid = threadIdx.x >> 6, lane = threadIdx.x & 63;
    const size_t row = (size_t)blockIdx.x * 4 + wid;
    const float4* xr = (const float4*)(x + row * C_DIM) + lane * 2;
    float4 a = xr[0], b = xr[1];
    float ss = a.x * a.x + a.y * a.y + a.z * a.z + a.w * a.w +
               b.x * b.x + b.y * b.y + b.z * b.z + b.w * b.w;
#pragma unroll
    for (int m = 1; m < 64; m <<= 1) ss += __shfl_xor(ss, m);
    float sc = 1.0f / fmaxf(sqrtf(ss), 1e-12f);
    int w0 = __builtin_amdgcn_cvt_pk_fp8_f32(a.x * sc, a.y * sc, 0, false);
    w0 = __builtin_amdgcn_cvt_pk_fp8_f32(a.z * sc, a.w * sc, w0, true);
    int w1 = __builtin_amdgcn_cvt_pk_fp8_f32(b.x * sc, b.y * sc, 0, false);
    w1 = __builtin_amdgcn_cvt_pk_fp8_f32(b.z * sc, b.w * sc, w1, true);
    int2 o2; o2.x = w0; o2.y = w1;
    *(int2*)(nf8 + row * C_DIM + lane * 8) = o2;
}

// ---- 256x256 fp8 symmetric GEMM, BK=64, double-buffered issue-ahead 2-phase ----
// 8 waves (2x4), wave tile 128x64; LDS 64 KB -> 2 blocks/CU.
// swizzle: 16-B granule ^= (row>>1)&3 (fragment lanes R,R+8 alias -> 2-way, free).
__global__ __launch_bounds__(512, 2) void gemm_sim256(const unsigned char* __restrict__ nf8,
                                                      unsigned short* __restrict__ simk) {
    __shared__ __align__(16) unsigned char smem[2][32768];   // [buf][A 16K | B 16K]
    const int idp = (NTRI2 - 1) - (int)blockIdx.x;           // row-major triangle order
    int u = (int)((sqrtf(8.0f * (float)idp + 1.0f) - 1.0f) * 0.5f);
    while (u * (u + 1) / 2 > idp) --u;
    while ((u + 1) * (u + 2) / 2 <= idp) ++u;
    const int v = idp - u * (u + 1) / 2;
    const int tI = (NT2 - 1) - u;
    const int tJ = (NT2 - 1) - v;

    const int tid = threadIdx.x;
    const int wid = tid >> 6, lane = tid & 63;
    const int wm = wid >> 2, wn = wid & 3;                   // 2 x 4 wave grid
    const int gr = tI * 256, gc = tJ * 256;
    f32x4 zero = {0.f, 0.f, 0.f, 0.f};
    f32x4 acc[8][4];
#pragma unroll
    for (int m = 0; m < 8; ++m)
#pragma unroll
        for (int n = 0; n < 4; ++n) acc[m][n] = zero;

    const int slr = lane >> 2;       // row within 16-row staging chunk
    const int slg = lane & 3;        // 16-B granule

    // stage K-tile k0 into buffer b: A/B each 16 chunks of (16 rows x 64 B)
#define STAGE(b, k0)                                                              \
    {                                                                             \
        _Pragma("unroll")                                                         \
        for (int i = 0; i < 2; ++i) {                                             \
            const int chunk = wid * 2 + i;                                        \
            const int r = chunk * 16 + slr;                                       \
            const int sc = (slg ^ ((r >> 1) & 3)) << 4;                           \
            gl_lds16b(nf8 + (size_t)(gr + r) * C_DIM + (k0) + sc,                 \
                      &smem[b][chunk * 1024]);                                    \
            gl_lds16b(nf8 + (size_t)(gc + r) * C_DIM + (k0) + sc,                 \
                      &smem[b][16384 + chunk * 1024]);                            \
        }                                                                         \
    }

    STAGE(0, 0)
    __syncthreads();
    int cur = 0;
    for (int t = 0; t < 8; ++t) {                            // 8 K-steps of 64 fp8 elems
        if (t + 1 < 8) STAGE(cur ^ 1, (t + 1) * 64)          // issue-ahead
        const unsigned char* As8 = &smem[cur][0];
        const unsigned char* Bs8 = &smem[cur][16384];
#pragma unroll
        for (int kk = 0; kk < 2; ++kk) {
            const int krow = kk * 32 + (lane >> 4) * 8;      // byte offset of 8-elem chunk
            long a[8], b[4];
#pragma unroll
            for (int m = 0; m < 8; ++m) {
                const int R = wm * 128 + m * 16 + (lane & 15);
                a[m] = *(const long*)&As8[R * 64 + (krow ^ (((R >> 1) & 3) << 4))];
            }
#pragma unroll
            for (int n = 0; n < 4; ++n) {
                const int R = wn * 64 + n * 16 + (lane & 15);
                b[n] = *(const long*)&Bs8[R * 64 + (krow ^ (((R >> 1) & 3) << 4))];
            }
#pragma unroll
            for (int m = 0; m < 8; ++m)
#pragma unroll
                for (int n = 0; n < 4; ++n)
                    acc[m][n] = __builtin_amdgcn_mfma_f32_16x16x32_fp8_fp8(a[m], b[n], acc[m][n], 0, 0, 0);
        }
        __syncthreads();                                     // next buffer ready
        cur ^= 1;
    }
#undef STAGE

    // pre-pack keys; C/D layout: col=lane&15, row=(lane>>4)*4+j
    unsigned short kk8[8][4][4];
#pragma unroll
    for (int m = 0; m < 8; ++m)
#pragma unroll
        for (int n = 0; n < 4; ++n)
#pragma unroll
            for (int j = 0; j < 4; ++j)
                kk8[m][n][j] = (unsigned short)negkey(f2bf(acc[m][n][j]));

    unsigned short* Cs = (unsigned short*)&smem[0][0];       // 128*136 shorts = 34816 B
    const int fc = lane & 15;
    const int fr = (lane >> 4) << 2;
    const bool mirror = (tJ > tI);

    // ---- direct writes: 4 quadrant passes (row-major bounce, stride 136) ----
#pragma unroll
    for (int qm = 0; qm < 2; ++qm)
#pragma unroll
        for (int qn = 0; qn < 2; ++qn) {
            __syncthreads();
            if (wm == qm && (wn >> 1) == qn) {
#pragma unroll
                for (int m = 0; m < 8; ++m)
#pragma unroll
                    for (int n = 0; n < 4; ++n) {
                        const int rl = m * 16 + fr;
                        const int cl = (wn & 1) * 64 + n * 16 + fc;
#pragma unroll
                        for (int j = 0; j < 4; ++j)
                            Cs[(rl + j) * 136 + cl] = kk8[m][n][j];
                    }
            }
            __syncthreads();
#pragma unroll
            for (int k = 0; k < 4; ++k) {
                const int lin = tid + k * 512;
                const int r = lin >> 4;
                const int c0 = (lin & 15) * 8;
                i32x4 vv = *(const i32x4*)&Cs[r * 136 + c0];
                __builtin_nontemporal_store(vv,
                    (i32x4*)&simk[(size_t)(gr + qm * 128 + r) * B_N + gc + qn * 128 + c0]);
            }
        }

    if (mirror) {
        // ---- transposed writes: 4 quadrant passes (col-major bounce) ----
#pragma unroll
        for (int qm = 0; qm < 2; ++qm)
#pragma unroll
            for (int qn = 0; qn < 2; ++qn) {
                __syncthreads();
                if (wm == qm && (wn >> 1) == qn) {
#pragma unroll
                    for (int m = 0; m < 8; ++m)
#pragma unroll
                        for (int n = 0; n < 4; ++n) {
                            const int rl = m * 16 + fr;
                            const int cl = (wn & 1) * 64 + n * 16 + fc;
                            ushort4 pk;
                            pk.x = kk8[m][n][0]; pk.y = kk8[m][n][1];
                            pk.z = kk8[m][n][2]; pk.w = kk8[m][n][3];
                            *(ushort4*)&Cs[cl * 136 + rl] = pk;
                        }
                }
                __syncthreads();
#pragma unroll
                for (int k = 0; k < 4; ++k) {
                    const int lin = tid + k * 512;
                    const int c = lin >> 4;
                    const int r0 = (lin & 15) * 8;
                    i32x4 vv = *(const i32x4*)&Cs[c * 136 + r0];
                    __builtin_nontemporal_store(vv,
                        (i32x4*)&simk[(size_t)(gc + qn * 128 + c) * B_N + gr + qm * 128 + r0]);
                }
            }
    }
}

// ---- 128-tile fp8 GEMM (chunked fallback path; R20 structure) ----
__global__ __launch_bounds__(256) void gemm_sim(const unsigned char* __restrict__ nf8,
                                                unsigned short* __restrict__ simk,
                                                int rowBase) {
    __shared__ __align__(16) unsigned char smemB[34816];
    unsigned char* As8 = smemB;
    unsigned char* Bs8 = smemB + 16384;
    const int tI = blockIdx.y, tJ = blockIdx.x;
    const int tid = threadIdx.x;
    const int wid = tid >> 6, lane = tid & 63;
    const int wm = wid >> 1, wn = wid & 1;
    const int gr = rowBase + tI * 128;
    const int gc = tJ * 128;
    f32x4 zero = {0.f, 0.f, 0.f, 0.f};
    f32x4 acc[4][4];
#pragma unroll
    for (int m = 0; m < 4; ++m)
#pragma unroll
        for (int n = 0; n < 4; ++n) acc[m][n] = zero;
    const int lr = lane >> 3, lcb = lane & 7;
    for (int k0 = 0; k0 < C_DIM; k0 += 128) {
#pragma unroll
        for (int i = 0; i < 4; ++i) {
            const int chunk = wid * 4 + i;
            const int r = chunk * 8 + lr;
            const int sc = (lcb ^ (r & 7)) << 4;
            gl_lds16b(nf8 + (size_t)(gr + r) * C_DIM + k0 + sc, As8 + chunk * 1024);
            gl_lds16b(nf8 + (size_t)(gc + r) * C_DIM + k0 + sc, Bs8 + chunk * 1024);
        }
        __syncthreads();
#pragma unroll
        for (int kk = 0; kk < 4; ++kk) {
            const int krow = kk * 32 + (lane >> 4) * 8;
            long a[4], b[4];
#pragma unroll
            for (int m = 0; m < 4; ++m) {
                const int R = wm * 64 + m * 16 + (lane & 15);
                a[m] = *(const long*)&As8[R * 128 + (krow ^ ((R & 7) << 4))];
            }
#pragma unroll
            for (int n = 0; n < 4; ++n) {
                const int R = wn * 64 + n * 16 + (lane & 15);
                b[n] = *(const long*)&Bs8[R * 128 + (krow ^ ((R & 7) << 4))];
            }
#pragma unroll
            for (int m = 0; m < 4; ++m)
#pragma unroll
                for (int n = 0; n < 4; ++n)
                    acc[m][n] = __builtin_amdgcn_mfma_f32_16x16x32_fp8_fp8(a[m], b[n], acc[m][n], 0, 0, 0);
        }
        __syncthreads();
    }
    unsigned short kk4[4][4][4];
#pragma unroll
    for (int m = 0; m < 4; ++m)
#pragma unroll
        for (int n = 0; n < 4; ++n)
#pragma unroll
            for (int j = 0; j < 4; ++j)
                kk4[m][n][j] = (unsigned short)negkey(f2bf(acc[m][n][j]));
    unsigned short* Cs = (unsigned short*)smemB;
    const int fc = (lane & 15);
    const int fr = (lane >> 4) << 2;
#pragma unroll
    for (int m = 0; m < 4; ++m)
#pragma unroll
        for (int n = 0; n < 4; ++n) {
            const int c = wn * 64 + n * 16 + fc;
            const int r0 = wm * 64 + m * 16 + fr;
#pragma unroll
            for (int j = 0; j < 4; ++j)
                Cs[(r0 + j) * 136 + c] = kk4[m][n][j];
        }
    __syncthreads();
#pragma unroll
    for (int k = 0; k < 8; ++k) {
        const int lin = tid + k * 256;
        const int r = lin >> 4;
        const int c0 = (lin & 15) * 8;
        i32x4 v = *(const i32x4*)&Cs[r * 136 + c0];
        __builtin_nontemporal_store(v, (i32x4*)&simk[(size_t)(gr - rowBase + r) * B_N + gc + c0]);
    }
}

// ---- block-per-row selection + loss: candidate compaction above TGKEY, exact bisect ----
__global__ __launch_bounds__(256) void select_loss(const unsigned short* __restrict__ simk,
                                                   const unsigned char* __restrict__ tgb,
                                                   const unsigned int* __restrict__ cm2,
                                                   const unsigned short* __restrict__ clist,
                                                   const int* __restrict__ off,
                                                   float* __restrict__ out, int rowBase) {
    __shared__ int nlist[256];
    __shared__ float s_partial[4];
    __shared__ int nln, s_cnt;

    const int tid = threadIdx.x;
    const int wid = tid >> 6, lane = tid & 63;
    const int row = rowBase + blockIdx.x;
    const unsigned short* srow = simk + (size_t)blockIdx.x * B_N;
    const int ti = tgb[row];
    const int o0 = off[ti], o1 = off[ti + 1];

    int4 A[4];
    const unsigned m = cm2[ti * 256 + tid];
#pragma unroll
    for (int q = 0; q < 4; ++q) {
        A[q] = *(const int4*)(srow + q * 2048 + tid * 8);
#pragma unroll
        for (int d = 0; d < 4; ++d) {
            unsigned two = (m >> (q * 8 + d * 2)) & 3u;
            unsigned kill = ((two & 1u) * 0xFFFFu) | (((two >> 1) & 1u) * 0xFFFF0000u);
            int v = (d == 0 ? A[q].x : d == 1 ? A[q].y : d == 2 ? A[q].z : A[q].w);
            v = (int)((unsigned)v & ~kill);
            if (d == 0) A[q].x = v; else if (d == 1) A[q].y = v;
            else if (d == 2) A[q].z = v; else A[q].w = v;
        }
    }
    if (tid == 0) { nln = 0; s_cnt = 0; }
    __syncthreads();                                             // B1

#define ELEM_LOOP(BODY)                                                          \
    _Pragma("unroll")                                                            \
    for (int q = 0; q < 4; ++q) {                                                \
        _Pragma("unroll")                                                        \
        for (int d = 0; d < 4; ++d) {                                            \
            unsigned w32 = (unsigned)(d == 0 ? A[q].x : d == 1 ? A[q].y          \
                                    : d == 2 ? A[q].z : A[q].w);                 \
            _Pragma("unroll")                                                    \
            for (int h2 = 0; h2 < 2; ++h2) {                                     \
                unsigned key = h2 ? (w32 >> 16) : (w32 & 0xFFFFu);               \
                BODY                                                             \
            }                                                                    \
        }                                                                        \
    }

    ELEM_LOOP(
        if (key > TGKEY) { int p = atomicAdd(&nln, 1); if (p < 256) nlist[p] = (int)key; }
    )
    __syncthreads();                                             // B2
    const int NC = nln;

    unsigned thr;
    int kremf;
    float S;

    if (NC >= 64 && NC <= 256) {
        if (wid != 0) return;
        unsigned pk[8];
#pragma unroll
        for (int s2 = 0; s2 < 8; ++s2) {
            int idx = o0 + lane + s2 * 64;
            pk[s2] = (idx < o1)
                ? ((((unsigned)srow[clist[idx]]) << 9) | ((unsigned)lane << 3) | (unsigned)s2)
                : 0xFFFFFFFFu;
        }
        int4 cw = *(const int4*)&nlist[lane * 4];
        unsigned cand[4] = {(unsigned)cw.x, (unsigned)cw.y, (unsigned)cw.z, (unsigned)cw.w};
#pragma unroll
        for (int j = 0; j < 4; ++j)
            if (lane * 4 + j >= NC) cand[j] = 0;
        unsigned cur = 0;
#pragma unroll
        for (int bit = 15; bit >= 0; --bit) {
            unsigned trial = cur | (1u << bit);
            int c = (cand[0] >= trial) + (cand[1] >= trial) +
                    (cand[2] >= trial) + (cand[3] >= trial);
#pragma unroll
            for (int o = 1; o < 64; o <<= 1) c += __shfl_xor(c, o);
            if (c >= 64) cur = trial;
        }
        int r = (cand[0] > cur) + (cand[1] > cur) + (cand[2] > cur) + (cand[3] > cur);
#pragma unroll
        for (int o = 1; o < 64; o <<= 1) r += __shfl_xor(r, o);
        kremf = 64 - r;
        float f = 0.f;
#pragma unroll
        for (int j = 0; j < 4; ++j)
            if (cand[j] > cur) f += __expf(2.0f * bf2f(unkey(cand[j])));
#pragma unroll
        for (int o = 1; o < 64; o <<= 1) f += __shfl_xor(f, o);
        S = f;
        thr = cur;

        S += (float)kremf * __expf(2.0f * bf2f(unkey(thr)));
        float acc = 0.f;
#pragma unroll
        for (int rd = 0; rd < 8; ++rd) {
            unsigned best = pk[0];
#pragma unroll
            for (int s2 = 1; s2 < 8; ++s2) best = best < pk[s2] ? best : pk[s2];
#pragma unroll
            for (int o = 1; o < 64; o <<= 1) {
                unsigned v = (unsigned)__shfl_xor((int)best, o);
                best = best < v ? best : v;
            }
            if (best != 0xFFFFFFFFu) {
                if (lane == (int)((best >> 3) & 63u)) pk[best & 7u] = 0xFFFFFFFFu;
                if (lane == 0) {
                    float p = bf2f(unkey(best >> 9));
                    acc += logf(__expf(2.0f * p) + S) - 2.0f * p;
                }
            }
        }
        if (lane == 0) out[row] = acc * 0.125f;
    } else {
        unsigned cur = 0;
        for (int bit = 15; bit >= 0; --bit) {
            unsigned trial = cur | (1u << bit);
            int c = 0;
            ELEM_LOOP( c += (key >= trial) ? 1 : 0; )
#pragma unroll
            for (int o = 1; o < 64; o <<= 1) c += __shfl_xor(c, o);
            if (lane == 0) atomicAdd(&s_cnt, c);
            __syncthreads();
            int tot = s_cnt;
            __syncthreads();
            if (tid == 0) s_cnt = 0;
            __syncthreads();
            if (tot >= 64) cur = trial;
        }
        {
            int c = 0;
            ELEM_LOOP( c += (key > cur) ? 1 : 0; )
#pragma unroll
            for (int o = 1; o < 64; o <<= 1) c += __shfl_xor(c, o);
            if (lane == 0) atomicAdd(&s_cnt, c);
            __syncthreads();
        }
        const int r = s_cnt;
        kremf = 64 - r;
        {
            float f = 0.f;
            ELEM_LOOP( if (key > cur) f += __expf(2.0f * bf2f(unkey(key))); )
#pragma unroll
            for (int o = 1; o < 64; o <<= 1) f += __shfl_xor(f, o);
            if (lane == 0) s_partial[wid] = f;
            __syncthreads();
        }
        if (wid != 0) return;
        S = s_partial[0] + s_partial[1] + s_partial[2] + s_partial[3];
        thr = cur;

        unsigned pk[8];
#pragma unroll
        for (int s2 = 0; s2 < 8; ++s2) {
            int idx = o0 + lane + s2 * 64;
            pk[s2] = (idx < o1)
                ? ((((unsigned)srow[clist[idx]]) << 9) | ((unsigned)lane << 3) | (unsigned)s2)
                : 0xFFFFFFFFu;
        }
        S += (float)kremf * __expf(2.0f * bf2f(unkey(thr)));
        float acc = 0.f;
#pragma unroll
        for (int rd = 0; rd < 8; ++rd) {
            unsigned best = pk[0];
#pragma unroll
            for (int s2 = 1; s2 < 8; ++s2) best = best < pk[s2] ? best : pk[s2];
#pragma unroll
            for (int o = 1; o < 64; o <<= 1) {
                unsigned v = (unsigned)__shfl_xor((int)best, o);
                best = best < v ? best : v;
            }
            if (best != 0xFFFFFFFFu) {
                if (lane == (int)((best >> 3) & 63u)) pk[best & 7u] = 0xFFFFFFFFu;
                if (lane == 0) {
                    float p = bf2f(unkey(best >> 9));
                    acc += logf(__expf(2.0f * p) + S) - 2.0f * p;
                }
            }
        }
        if (lane == 0) out[row] = acc * 0.125f;
    }
#undef ELEM_LOOP
}

extern "C" void kernel_launch(void* const* d_in, const int* in_sizes, int n_in,
                              void* d_out, int out_size, void* d_ws, size_t ws_size,
                              hipStream_t stream) {
    const float* newf = (const float*)d_in[1];
    const unsigned int* tgtw = (const unsigned int*)d_in[2];
    float* out = (float*)d_out;
    char* ws = (char*)d_ws;
    unsigned char* tgb = (unsigned char*)ws;                          // 8 KB
    unsigned int* cm2 = (unsigned int*)(ws + 8192);                   // 100 KB
    int* off = (int*)(ws + 110592);                                   // 1 KB (129 ints)
    unsigned short* clist = (unsigned short*)(ws + 111616);           // 16 KB
    unsigned char* nf8 = (unsigned char*)(ws + 131072);               // 4 MB fp8 (aligned)
    unsigned short* simk = (unsigned short*)(ws + 131072 + ((size_t)4 << 20));

    size_t fixed = 131072 + ((size_t)4 << 20);
    size_t avail = (ws_size > fixed) ? (ws_size - fixed) : 0;
    long maxRows = (long)(avail / ((size_t)B_N * 2));
    int chunk = (int)((maxRows / 128) * 128);
    if (chunk < 128) chunk = 128;
    if (chunk > B_N) chunk = B_N;

    hipLaunchKernelGGL(prep_all, dim3(1), dim3(256), 0, stream, tgtw, tgb, clist, off);
    hipLaunchKernelGGL(class_masks, dim3(100), dim3(256), 0, stream, tgb, cm2);
    hipLaunchKernelGGL(normalize_k, dim3(B_N / 4), dim3(256), 0, stream, newf, nf8);
    if (chunk == B_N) {
        hipLaunchKernelGGL(gemm_sim256, dim3(NTRI2), dim3(512), 0, stream, nf8, simk);
        hipLaunchKernelGGL(select_loss, dim3(B_N), dim3(256), 0, stream,
                           simk, tgb, cm2, clist, off, out, 0);
    } else {
        for (int r0 = 0; r0 < B_N; r0 += chunk) {
            int rows = (B_N - r0 < chunk) ? (B_N - r0) : chunk;
            hipLaunchKernelGGL(gemm_sim, dim3(NT, rows / 128), dim3(256), 0, stream,
                               nf8, simk, r0);
            hipLaunchKernelGGL(select_loss, dim3(rows), dim3(256), 0, stream,
                               simk, tgb, cm2, clist, off, out, r0);
        }
    }
}

// Round 22
// 120.999 us; speedup vs baseline: 1.1988x; 1.1988x over previous
//
#include <hip/hip_runtime.h>
#include <hip/hip_bf16.h>

#define B_N 8192
#define C_DIM 512
#define NT 64            // 128-wide tiles per dimension
#define NTRI 2080        // NT*(NT+1)/2 upper-triangle tiles
#define TGKEY 0xBDC0u    // negkey(bf16 0.09375): conservative top-64 pre-threshold

typedef __attribute__((ext_vector_type(4))) float f32x4;
typedef __attribute__((ext_vector_type(4))) int i32x4;
typedef __attribute__((address_space(3))) unsigned int lds_u32;
typedef const __attribute__((address_space(1))) unsigned int glb_u32;

__device__ __forceinline__ void gl_lds16b(const unsigned char* g, unsigned char* l) {
    __builtin_amdgcn_global_load_lds((glb_u32*)g, (lds_u32*)l, 16, 0, 0);
}

__device__ __forceinline__ unsigned short f2bf(float f) {
    unsigned int u = __float_as_uint(f);
    u += 0x7FFFu + ((u >> 16) & 1u);          // RNE
    return (unsigned short)(u >> 16);
}
__device__ __forceinline__ float bf2f(unsigned int s) {
    return __uint_as_float(s << 16);
}
// order-preserving key: float order -> unsigned ascending. key 0 impossible for finite sims.
__device__ __forceinline__ unsigned negkey(unsigned ub) {
    return (ub & 0x8000u) ? ((~ub) & 0xFFFFu) : (ub | 0x8000u);
}
__device__ __forceinline__ unsigned unkey(unsigned k) {
    return (k & 0x8000u) ? (k ^ 0x8000u) : ((~k) & 0xFFFFu);
}

// ---- one-block prep: layout detect, class bytes, class member lists (counting sort) ----
__global__ void prep_all(const unsigned int* __restrict__ t, unsigned char* __restrict__ tgb,
                         unsigned short* __restrict__ clist, int* __restrict__ off) {
    __shared__ int bad, cnt[128], base[128];
    const int tid = threadIdx.x;
    if (tid == 0) bad = 0;
    if (tid < 128) cnt[tid] = 0;
    __syncthreads();
    int local = 0;
    for (int k = tid; k < 4096; k += 256)        // first 32KB only: safe for both layouts
        if (t[2 * k + 1] != 0u) local = 1;
    if (local) atomicOr(&bad, 1);
    __syncthreads();
    const int is64 = (bad == 0);
    for (int i = 0; i < 32; ++i) {
        int j = i * 256 + tid;
        unsigned c = (is64 ? t[2 * j] : t[j]) & 127u;   // classes < 100
        tgb[j] = (unsigned char)c;
        atomicAdd(&cnt[c], 1);
    }
    __syncthreads();
    if (tid == 0) {
        int s = 0;
        for (int c = 0; c < 128; ++c) { base[c] = s; off[c] = s; s += cnt[c]; }
        off[128] = s;
    }
    __syncthreads();
    for (int i = 0; i < 32; ++i) {
        int j = i * 256 + tid;
        unsigned c = (is64 ? t[2 * j] : t[j]) & 127u;
        int idx = atomicAdd(&base[c], 1);
        clist[idx] = (unsigned short)j;
    }
}

// ---- per-class membership words: cm2[c*256+t] bit (q*8+e) = (tgb[q*2048+t*8+e]==c) ----
__global__ void class_masks(const unsigned char* __restrict__ tgb,
                            unsigned int* __restrict__ cm2) {
    const int c = blockIdx.x, t = threadIdx.x;
    unsigned w = 0;
#pragma unroll
    for (int q = 0; q < 4; ++q) {
        const unsigned char* base = tgb + q * 2048 + t * 8;
        unsigned b = 0;
#pragma unroll
        for (int e = 0; e < 8; ++e)
            b |= ((unsigned)(base[e] == c)) << e;
        w |= b << (8 * q);
    }
    cm2[c * 256 + t] = w;
}

// ---- L2 normalize rows, emit OCP e4m3 fp8 ----
__global__ __launch_bounds__(256) void normalize_k(const float* __restrict__ x,
                                                   unsigned char* __restrict__ nf8) {
    const int wid = threadIdx.x >> 6, lane = threadIdx.x & 63;
    const size_t row = (size_t)blockIdx.x * 4 + wid;
    const float4* xr = (const float4*)(x + row * C_DIM) + lane * 2;
    float4 a = xr[0], b = xr[1];
    float ss = a.x * a.x + a.y * a.y + a.z * a.z + a.w * a.w +
               b.x * b.x + b.y * b.y + b.z * b.z + b.w * b.w;
#pragma unroll
    for (int m = 1; m < 64; m <<= 1) ss += __shfl_xor(ss, m);
    float sc = 1.0f / fmaxf(sqrtf(ss), 1e-12f);
    int w0 = __builtin_amdgcn_cvt_pk_fp8_f32(a.x * sc, a.y * sc, 0, false);
    w0 = __builtin_amdgcn_cvt_pk_fp8_f32(a.z * sc, a.w * sc, w0, true);
    int w1 = __builtin_amdgcn_cvt_pk_fp8_f32(b.x * sc, b.y * sc, 0, false);
    w1 = __builtin_amdgcn_cvt_pk_fp8_f32(b.z * sc, b.w * sc, w1, true);
    int2 o2; o2.x = w0; o2.y = w1;
    *(int2*)(nf8 + row * C_DIM + lane * 8) = o2;
}

// ---- sim keys = negkey(bf16(nf8 @ nf8^T)), fp8 MFMA, 128x128 tiles ----
// BK=64 double-buffered issue-ahead 2-phase (STAGE t+1 before compute t);
// LDS 34816 (2 x 16KB buffers; Cs stride-136 bounce aliases) -> 4 blocks/CU;
// swizzle: 16-B granule ^= (R>>1)&3 (8 distinct banks over R&7, 2 lanes/bank);
// non-temporal simk stores keep nf8 L3-resident.
__global__ __launch_bounds__(256) void gemm_sim(const unsigned char* __restrict__ nf8,
                                                unsigned short* __restrict__ simk,
                                                int rowBase, int symmetric) {
    __shared__ __align__(16) unsigned char smemB[34816];
    int tI, tJ;
    if (symmetric) {
        const int idp = (NTRI - 1) - (int)blockIdx.x;   // row-major triangle order
        int u = (int)((sqrtf(8.0f * (float)idp + 1.0f) - 1.0f) * 0.5f);
        while (u * (u + 1) / 2 > idp) --u;
        while ((u + 1) * (u + 2) / 2 <= idp) ++u;
        const int v = idp - u * (u + 1) / 2;
        tI = (NT - 1) - u;
        tJ = (NT - 1) - v;
    } else {
        tI = blockIdx.y; tJ = blockIdx.x;
    }
    const int tid = threadIdx.x;
    const int wid = tid >> 6, lane = tid & 63;
    const int wm = wid >> 1, wn = wid & 1;
    const int gr = rowBase + tI * 128;
    const int gc = tJ * 128;
    f32x4 zero = {0.f, 0.f, 0.f, 0.f};
    f32x4 acc[4][4];
#pragma unroll
    for (int m = 0; m < 4; ++m)
#pragma unroll
        for (int n = 0; n < 4; ++n) acc[m][n] = zero;

    const int slr = lane >> 2;       // row within 16-row staging chunk
    const int slg = lane & 3;        // 16-B granule

    // buffer b: A at b*16384, B at b*16384+8192; each 8 chunks of (16 rows x 64 B)
#define STAGE(b, k0)                                                              \
    {                                                                             \
        _Pragma("unroll")                                                         \
        for (int i = 0; i < 2; ++i) {                                             \
            const int chunk = wid * 2 + i;              /* 0..7, wave-uniform */  \
            const int r = chunk * 16 + slr;                                       \
            const int sc = (slg ^ ((r >> 1) & 3)) << 4;                           \
            gl_lds16b(nf8 + (size_t)(gr + r) * C_DIM + (k0) + sc,                 \
                      smemB + (b) * 16384 + chunk * 1024);                        \
            gl_lds16b(nf8 + (size_t)(gc + r) * C_DIM + (k0) + sc,                 \
                      smemB + (b) * 16384 + 8192 + chunk * 1024);                 \
        }                                                                         \
    }

    STAGE(0, 0)
    __syncthreads();
    int cur = 0;
    for (int t = 0; t < 8; ++t) {                        // 8 K-steps of 64 fp8 elems
        if (t + 1 < 8) STAGE(cur ^ 1, (t + 1) * 64)      // issue-ahead into other buffer
        const unsigned char* As8 = smemB + cur * 16384;
        const unsigned char* Bs8 = As8 + 8192;
#pragma unroll
        for (int kk = 0; kk < 2; ++kk) {
            const int krow = kk * 32 + (lane >> 4) * 8;  // byte offset of 8-elem k-chunk
            long a[4], b[4];
#pragma unroll
            for (int m = 0; m < 4; ++m) {
                const int R = wm * 64 + m * 16 + (lane & 15);
                a[m] = *(const long*)&As8[R * 64 + (krow ^ (((R >> 1) & 3) << 4))];
            }
#pragma unroll
            for (int n = 0; n < 4; ++n) {
                const int R = wn * 64 + n * 16 + (lane & 15);
                b[n] = *(const long*)&Bs8[R * 64 + (krow ^ (((R >> 1) & 3) << 4))];
            }
#pragma unroll
            for (int m = 0; m < 4; ++m)
#pragma unroll
                for (int n = 0; n < 4; ++n)
                    acc[m][n] = __builtin_amdgcn_mfma_f32_16x16x32_fp8_fp8(a[m], b[n], acc[m][n], 0, 0, 0);
        }
        __syncthreads();                                 // drains vm+lgkm: next buffer ready
        cur ^= 1;
    }
#undef STAGE

    // pre-pack keys once; C/D layout: col=lane&15, row=(lane>>4)*4+j
    unsigned short kk4[4][4][4];
#pragma unroll
    for (int m = 0; m < 4; ++m)
#pragma unroll
        for (int n = 0; n < 4; ++n)
#pragma unroll
            for (int j = 0; j < 4; ++j)
                kk4[m][n][j] = (unsigned short)negkey(f2bf(acc[m][n][j]));

    unsigned short* Cs = (unsigned short*)smemB;         // 128*136 shorts = 34816 B
    const int fc = (lane & 15);
    const int fr = (lane >> 4) << 2;

    // ---- direct (row-major) write via row-major bounce (stride 136) ----
#pragma unroll
    for (int m = 0; m < 4; ++m)
#pragma unroll
        for (int n = 0; n < 4; ++n) {
            const int c = wn * 64 + n * 16 + fc;
            const int r0 = wm * 64 + m * 16 + fr;
#pragma unroll
            for (int j = 0; j < 4; ++j)
                Cs[(r0 + j) * 136 + c] = kk4[m][n][j];
        }
    __syncthreads();
#pragma unroll
    for (int k = 0; k < 8; ++k) {
        const int lin = tid + k * 256;
        const int r = lin >> 4;
        const int c0 = (lin & 15) * 8;
        i32x4 v = *(const i32x4*)&Cs[r * 136 + c0];
        __builtin_nontemporal_store(v, (i32x4*)&simk[(size_t)(gr - rowBase + r) * B_N + gc + c0]);
    }

    if (symmetric && tJ > tI) {
        // ---- transposed write via col-major bounce (stride 136) ----
        __syncthreads();
#pragma unroll
        for (int m = 0; m < 4; ++m)
#pragma unroll
            for (int n = 0; n < 4; ++n) {
                const int c = wn * 64 + n * 16 + fc;
                const int r0 = wm * 64 + m * 16 + fr;
                ushort4 pk;
                pk.x = kk4[m][n][0]; pk.y = kk4[m][n][1];
                pk.z = kk4[m][n][2]; pk.w = kk4[m][n][3];
                *(ushort4*)&Cs[c * 136 + r0] = pk;
            }
        __syncthreads();
#pragma unroll
        for (int k = 0; k < 8; ++k) {
            const int lin = tid + k * 256;
            const int c = lin >> 4;
            const int r0 = (lin & 15) * 8;
            i32x4 v = *(const i32x4*)&Cs[c * 136 + r0];
            __builtin_nontemporal_store(v, (i32x4*)&simk[(size_t)(gc + c) * B_N + gr + r0]);
        }
    }
}

// ---- block-per-row selection + loss: candidate compaction above TGKEY, exact bisect ----
__global__ __launch_bounds__(256) void select_loss(const unsigned short* __restrict__ simk,
                                                   const unsigned char* __restrict__ tgb,
                                                   const unsigned int* __restrict__ cm2,
                                                   const unsigned short* __restrict__ clist,
                                                   const int* __restrict__ off,
                                                   float* __restrict__ out, int rowBase) {
    __shared__ int nlist[256];
    __shared__ float s_partial[4];
    __shared__ int nln, s_cnt;

    const int tid = threadIdx.x;
    const int wid = tid >> 6, lane = tid & 63;
    const int row = rowBase + blockIdx.x;
    const unsigned short* srow = simk + (size_t)blockIdx.x * B_N;
    const int ti = tgb[row];
    const int o0 = off[ti], o1 = off[ti + 1];

    // load 32 keys, mask same-class halves to 0 (key 0 < TGKEY: never a candidate)
    int4 A[4];
    const unsigned m = cm2[ti * 256 + tid];
#pragma unroll
    for (int q = 0; q < 4; ++q) {
        A[q] = *(const int4*)(srow + q * 2048 + tid * 8);
#pragma unroll
        for (int d = 0; d < 4; ++d) {
            unsigned two = (m >> (q * 8 + d * 2)) & 3u;
            unsigned kill = ((two & 1u) * 0xFFFFu) | (((two >> 1) & 1u) * 0xFFFF0000u);
            int v = (d == 0 ? A[q].x : d == 1 ? A[q].y : d == 2 ? A[q].z : A[q].w);
            v = (int)((unsigned)v & ~kill);
            if (d == 0) A[q].x = v; else if (d == 1) A[q].y = v;
            else if (d == 2) A[q].z = v; else A[q].w = v;
        }
    }
    if (tid == 0) { nln = 0; s_cnt = 0; }
    __syncthreads();                                             // B1

#define ELEM_LOOP(BODY)                                                          \
    _Pragma("unroll")                                                            \
    for (int q = 0; q < 4; ++q) {                                                \
        _Pragma("unroll")                                                        \
        for (int d = 0; d < 4; ++d) {                                            \
            unsigned w32 = (unsigned)(d == 0 ? A[q].x : d == 1 ? A[q].y          \
                                    : d == 2 ? A[q].z : A[q].w);                 \
            _Pragma("unroll")                                                    \
            for (int h2 = 0; h2 < 2; ++h2) {                                     \
                unsigned key = h2 ? (w32 >> 16) : (w32 & 0xFFFFu);               \
                BODY                                                             \
            }                                                                    \
        }                                                                        \
    }

    // single scan: compact candidates above the conservative pre-threshold
    ELEM_LOOP(
        if (key > TGKEY) { int p = atomicAdd(&nln, 1); if (p < 256) nlist[p] = (int)key; }
    )
    __syncthreads();                                             // B2
    const int NC = nln;

    unsigned thr;
    int kremf;
    float S;

    if (NC >= 64 && NC <= 256) {
        // -------- fast path: wave0 solo; waves 1-3 exit now --------
        if (wid != 0) return;
        unsigned pk[8];
#pragma unroll
        for (int s2 = 0; s2 < 8; ++s2) {
            int idx = o0 + lane + s2 * 64;
            pk[s2] = (idx < o1)
                ? ((((unsigned)srow[clist[idx]]) << 9) | ((unsigned)lane << 3) | (unsigned)s2)
                : 0xFFFFFFFFu;
        }
        int4 cw = *(const int4*)&nlist[lane * 4];
        unsigned cand[4] = {(unsigned)cw.x, (unsigned)cw.y, (unsigned)cw.z, (unsigned)cw.w};
#pragma unroll
        for (int j = 0; j < 4; ++j)
            if (lane * 4 + j >= NC) cand[j] = 0;
        unsigned cur = 0;
#pragma unroll
        for (int bit = 15; bit >= 0; --bit) {
            unsigned trial = cur | (1u << bit);
            int c = (cand[0] >= trial) + (cand[1] >= trial) +
                    (cand[2] >= trial) + (cand[3] >= trial);
#pragma unroll
            for (int o = 1; o < 64; o <<= 1) c += __shfl_xor(c, o);
            if (c >= 64) cur = trial;
        }
        int r = (cand[0] > cur) + (cand[1] > cur) + (cand[2] > cur) + (cand[3] > cur);
#pragma unroll
        for (int o = 1; o < 64; o <<= 1) r += __shfl_xor(r, o);
        kremf = 64 - r;
        float f = 0.f;
#pragma unroll
        for (int j = 0; j < 4; ++j)
            if (cand[j] > cur) f += __expf(2.0f * bf2f(unkey(cand[j])));
#pragma unroll
        for (int o = 1; o < 64; o <<= 1) f += __shfl_xor(f, o);
        S = f;
        thr = cur;

        S += (float)kremf * __expf(2.0f * bf2f(unkey(thr)));
        float acc = 0.f;
#pragma unroll
        for (int rd = 0; rd < 8; ++rd) {
            unsigned best = pk[0];
#pragma unroll
            for (int s2 = 1; s2 < 8; ++s2) best = best < pk[s2] ? best : pk[s2];
#pragma unroll
            for (int o = 1; o < 64; o <<= 1) {
                unsigned v = (unsigned)__shfl_xor((int)best, o);
                best = best < v ? best : v;
            }
            if (best != 0xFFFFFFFFu) {
                if (lane == (int)((best >> 3) & 63u)) pk[best & 7u] = 0xFFFFFFFFu;
                if (lane == 0) {
                    float p = bf2f(unkey(best >> 9));
                    acc += logf(__expf(2.0f * p) + S) - 2.0f * p;
                }
            }
        }
        if (lane == 0) out[row] = acc * 0.125f;
    } else {
        // -------- exact fallback (distribution-independent): block-wide bisection --------
        unsigned cur = 0;
        for (int bit = 15; bit >= 0; --bit) {
            unsigned trial = cur | (1u << bit);
            int c = 0;
            ELEM_LOOP( c += (key >= trial) ? 1 : 0; )
#pragma unroll
            for (int o = 1; o < 64; o <<= 1) c += __shfl_xor(c, o);
            if (lane == 0) atomicAdd(&s_cnt, c);
            __syncthreads();
            int tot = s_cnt;
            __syncthreads();
            if (tid == 0) s_cnt = 0;
            __syncthreads();
            if (tot >= 64) cur = trial;
        }
        {
            int c = 0;
            ELEM_LOOP( c += (key > cur) ? 1 : 0; )
#pragma unroll
            for (int o = 1; o < 64; o <<= 1) c += __shfl_xor(c, o);
            if (lane == 0) atomicAdd(&s_cnt, c);
            __syncthreads();
        }
        const int r = s_cnt;
        kremf = 64 - r;
        {
            float f = 0.f;
            ELEM_LOOP( if (key > cur) f += __expf(2.0f * bf2f(unkey(key))); )
#pragma unroll
            for (int o = 1; o < 64; o <<= 1) f += __shfl_xor(f, o);
            if (lane == 0) s_partial[wid] = f;
            __syncthreads();
        }
        if (wid != 0) return;
        S = s_partial[0] + s_partial[1] + s_partial[2] + s_partial[3];
        thr = cur;

        unsigned pk[8];
#pragma unroll
        for (int s2 = 0; s2 < 8; ++s2) {
            int idx = o0 + lane + s2 * 64;
            pk[s2] = (idx < o1)
                ? ((((unsigned)srow[clist[idx]]) << 9) | ((unsigned)lane << 3) | (unsigned)s2)
                : 0xFFFFFFFFu;
        }
        S += (float)kremf * __expf(2.0f * bf2f(unkey(thr)));
        float acc = 0.f;
#pragma unroll
        for (int rd = 0; rd < 8; ++rd) {
            unsigned best = pk[0];
#pragma unroll
            for (int s2 = 1; s2 < 8; ++s2) best = best < pk[s2] ? best : pk[s2];
#pragma unroll
            for (int o = 1; o < 64; o <<= 1) {
                unsigned v = (unsigned)__shfl_xor((int)best, o);
                best = best < v ? best : v;
            }
            if (best != 0xFFFFFFFFu) {
                if (lane == (int)((best >> 3) & 63u)) pk[best & 7u] = 0xFFFFFFFFu;
                if (lane == 0) {
                    float p = bf2f(unkey(best >> 9));
                    acc += logf(__expf(2.0f * p) + S) - 2.0f * p;
                }
            }
        }
        if (lane == 0) out[row] = acc * 0.125f;
    }
#undef ELEM_LOOP
}

extern "C" void kernel_launch(void* const* d_in, const int* in_sizes, int n_in,
                              void* d_out, int out_size, void* d_ws, size_t ws_size,
                              hipStream_t stream) {
    const float* newf = (const float*)d_in[1];
    const unsigned int* tgtw = (const unsigned int*)d_in[2];
    float* out = (float*)d_out;
    char* ws = (char*)d_ws;
    unsigned char* tgb = (unsigned char*)ws;                          // 8 KB
    unsigned int* cm2 = (unsigned int*)(ws + 8192);                   // 100 KB
    int* off = (int*)(ws + 110592);                                   // 1 KB (129 ints)
    unsigned short* clist = (unsigned short*)(ws + 111616);           // 16 KB
    unsigned char* nf8 = (unsigned char*)(ws + 131072);               // 4 MB fp8 (aligned)
    unsigned short* simk = (unsigned short*)(ws + 131072 + ((size_t)4 << 20));

    size_t fixed = 131072 + ((size_t)4 << 20);
    size_t avail = (ws_size > fixed) ? (ws_size - fixed) : 0;
    long maxRows = (long)(avail / ((size_t)B_N * 2));
    int chunk = (int)((maxRows / 128) * 128);
    if (chunk < 128) chunk = 128;
    if (chunk > B_N) chunk = B_N;

    hipLaunchKernelGGL(prep_all, dim3(1), dim3(256), 0, stream, tgtw, tgb, clist, off);
    hipLaunchKernelGGL(class_masks, dim3(100), dim3(256), 0, stream, tgb, cm2);
    hipLaunchKernelGGL(normalize_k, dim3(B_N / 4), dim3(256), 0, stream, newf, nf8);
    if (chunk == B_N) {
        hipLaunchKernelGGL(gemm_sim, dim3(NTRI), dim3(256), 0, stream, nf8, simk, 0, 1);
        hipLaunchKernelGGL(select_loss, dim3(B_N), dim3(256), 0, stream,
                           simk, tgb, cm2, clist, off, out, 0);
    } else {
        for (int r0 = 0; r0 < B_N; r0 += chunk) {
            int rows = (B_N - r0 < chunk) ? (B_N - r0) : chunk;
            hipLaunchKernelGGL(gemm_sim, dim3(NT, rows / 128), dim3(256), 0, stream,
                               nf8, simk, r0, 0);
            hipLaunchKernelGGL(select_loss, dim3(rows), dim3(256), 0, stream,
                               simk, tgb, cm2, clist, off, out, r0);
        }
    }
}

// Round 23
// 117.966 us; speedup vs baseline: 1.2297x; 1.0257x over previous
//
#include <hip/hip_runtime.h>
#include <hip/hip_bf16.h>

#define B_N 8192
#define C_DIM 512
#define NT 64            // 128-wide tiles per dimension
#define NTRI 2080        // NT*(NT+1)/2 upper-triangle tiles
#define TGKEY 0xBDC0u    // negkey(bf16 0.09375): conservative top-64 pre-threshold

typedef __attribute__((ext_vector_type(4))) float f32x4;
typedef __attribute__((ext_vector_type(4))) int i32x4;
typedef __attribute__((address_space(3))) unsigned int lds_u32;
typedef const __attribute__((address_space(1))) unsigned int glb_u32;

__device__ __forceinline__ void gl_lds16b(const unsigned char* g, unsigned char* l) {
    __builtin_amdgcn_global_load_lds((glb_u32*)g, (lds_u32*)l, 16, 0, 0);
}

__device__ __forceinline__ unsigned short f2bf(float f) {
    unsigned int u = __float_as_uint(f);
    u += 0x7FFFu + ((u >> 16) & 1u);          // RNE
    return (unsigned short)(u >> 16);
}
__device__ __forceinline__ float bf2f(unsigned int s) {
    return __uint_as_float(s << 16);
}
// order-preserving key: float order -> unsigned ascending. key 0 impossible for finite sims.
__device__ __forceinline__ unsigned negkey(unsigned ub) {
    return (ub & 0x8000u) ? ((~ub) & 0xFFFFu) : (ub | 0x8000u);
}
__device__ __forceinline__ unsigned unkey(unsigned k) {
    return (k & 0x8000u) ? (k ^ 0x8000u) : ((~k) & 0xFFFFu);
}

// ---- one-block prep: layout detect, class bytes, class member lists (counting sort) ----
__global__ void prep_all(const unsigned int* __restrict__ t, unsigned char* __restrict__ tgb,
                         unsigned short* __restrict__ clist, int* __restrict__ off) {
    __shared__ int bad, cnt[128], base[128];
    const int tid = threadIdx.x;
    if (tid == 0) bad = 0;
    if (tid < 128) cnt[tid] = 0;
    __syncthreads();
    int local = 0;
    for (int k = tid; k < 4096; k += 256)        // first 32KB only: safe for both layouts
        if (t[2 * k + 1] != 0u) local = 1;
    if (local) atomicOr(&bad, 1);
    __syncthreads();
    const int is64 = (bad == 0);
    for (int i = 0; i < 32; ++i) {
        int j = i * 256 + tid;
        unsigned c = (is64 ? t[2 * j] : t[j]) & 127u;   // classes < 100
        tgb[j] = (unsigned char)c;
        atomicAdd(&cnt[c], 1);
    }
    __syncthreads();
    if (tid == 0) {
        int s = 0;
        for (int c = 0; c < 128; ++c) { base[c] = s; off[c] = s; s += cnt[c]; }
        off[128] = s;
    }
    __syncthreads();
    for (int i = 0; i < 32; ++i) {
        int j = i * 256 + tid;
        unsigned c = (is64 ? t[2 * j] : t[j]) & 127u;
        int idx = atomicAdd(&base[c], 1);
        clist[idx] = (unsigned short)j;
    }
}

// ---- per-class membership words: cm2[c*256+t] bit (q*8+e) = (tgb[q*2048+t*8+e]==c) ----
__global__ void class_masks(const unsigned char* __restrict__ tgb,
                            unsigned int* __restrict__ cm2) {
    const int c = blockIdx.x, t = threadIdx.x;
    unsigned w = 0;
#pragma unroll
    for (int q = 0; q < 4; ++q) {
        const unsigned char* base = tgb + q * 2048 + t * 8;
        unsigned b = 0;
#pragma unroll
        for (int e = 0; e < 8; ++e)
            b |= ((unsigned)(base[e] == c)) << e;
        w |= b << (8 * q);
    }
    cm2[c * 256 + t] = w;
}

// ---- L2 normalize rows, emit OCP e4m3 fp8 ----
__global__ __launch_bounds__(256) void normalize_k(const float* __restrict__ x,
                                                   unsigned char* __restrict__ nf8) {
    const int wid = threadIdx.x >> 6, lane = threadIdx.x & 63;
    const size_t row = (size_t)blockIdx.x * 4 + wid;
    const float4* xr = (const float4*)(x + row * C_DIM) + lane * 2;
    float4 a = xr[0], b = xr[1];
    float ss = a.x * a.x + a.y * a.y + a.z * a.z + a.w * a.w +
               b.x * b.x + b.y * b.y + b.z * b.z + b.w * b.w;
#pragma unroll
    for (int m = 1; m < 64; m <<= 1) ss += __shfl_xor(ss, m);
    float sc = 1.0f / fmaxf(sqrtf(ss), 1e-12f);
    int w0 = __builtin_amdgcn_cvt_pk_fp8_f32(a.x * sc, a.y * sc, 0, false);
    w0 = __builtin_amdgcn_cvt_pk_fp8_f32(a.z * sc, a.w * sc, w0, true);
    int w1 = __builtin_amdgcn_cvt_pk_fp8_f32(b.x * sc, b.y * sc, 0, false);
    w1 = __builtin_amdgcn_cvt_pk_fp8_f32(b.z * sc, b.w * sc, w1, true);
    int2 o2; o2.x = w0; o2.y = w1;
    *(int2*)(nf8 + row * C_DIM + lane * 8) = o2;
}

// ---- sim keys = negkey(bf16(nf8 @ nf8^T)), fp8 MFMA, 128x128 tiles ----
// BK=64 double-buffered issue-ahead; LDS exactly 32768 (2x16KB staging;
// epilogue Cs[64][136]=17.4KB half-pass bounce aliases) -> 5 blocks/CU;
// stride-136 keeps bank conflicts at the floor; non-temporal simk stores.
__global__ __launch_bounds__(256) void gemm_sim(const unsigned char* __restrict__ nf8,
                                                unsigned short* __restrict__ simk,
                                                int rowBase, int symmetric) {
    __shared__ __align__(16) unsigned char smemB[32768];
    int tI, tJ;
    if (symmetric) {
        const int idp = (NTRI - 1) - (int)blockIdx.x;   // row-major triangle order
        int u = (int)((sqrtf(8.0f * (float)idp + 1.0f) - 1.0f) * 0.5f);
        while (u * (u + 1) / 2 > idp) --u;
        while ((u + 1) * (u + 2) / 2 <= idp) ++u;
        const int v = idp - u * (u + 1) / 2;
        tI = (NT - 1) - u;
        tJ = (NT - 1) - v;
    } else {
        tI = blockIdx.y; tJ = blockIdx.x;
    }
    const int tid = threadIdx.x;
    const int wid = tid >> 6, lane = tid & 63;
    const int wm = wid >> 1, wn = wid & 1;
    const int gr = rowBase + tI * 128;
    const int gc = tJ * 128;
    f32x4 zero = {0.f, 0.f, 0.f, 0.f};
    f32x4 acc[4][4];
#pragma unroll
    for (int m = 0; m < 4; ++m)
#pragma unroll
        for (int n = 0; n < 4; ++n) acc[m][n] = zero;

    const int slr = lane >> 2;       // row within 16-row staging chunk
    const int slg = lane & 3;        // 16-B granule

    // buffer b: A at b*16384, B at b*16384+8192; each 8 chunks of (16 rows x 64 B)
#define STAGE(b, k0)                                                              \
    {                                                                             \
        _Pragma("unroll")                                                         \
        for (int i = 0; i < 2; ++i) {                                             \
            const int chunk = wid * 2 + i;              /* 0..7, wave-uniform */  \
            const int r = chunk * 16 + slr;                                       \
            const int sc = (slg ^ ((r >> 1) & 3)) << 4;                           \
            gl_lds16b(nf8 + (size_t)(gr + r) * C_DIM + (k0) + sc,                 \
                      smemB + (b) * 16384 + chunk * 1024);                        \
            gl_lds16b(nf8 + (size_t)(gc + r) * C_DIM + (k0) + sc,                 \
                      smemB + (b) * 16384 + 8192 + chunk * 1024);                 \
        }                                                                         \
    }

    STAGE(0, 0)
    __syncthreads();
    int cur = 0;
    for (int t = 0; t < 8; ++t) {                        // 8 K-steps of 64 fp8 elems
        if (t + 1 < 8) STAGE(cur ^ 1, (t + 1) * 64)      // issue-ahead into other buffer
        const unsigned char* As8 = smemB + cur * 16384;
        const unsigned char* Bs8 = As8 + 8192;
#pragma unroll
        for (int kk = 0; kk < 2; ++kk) {
            const int krow = kk * 32 + (lane >> 4) * 8;  // byte offset of 8-elem k-chunk
            long a[4], b[4];
#pragma unroll
            for (int m = 0; m < 4; ++m) {
                const int R = wm * 64 + m * 16 + (lane & 15);
                a[m] = *(const long*)&As8[R * 64 + (krow ^ (((R >> 1) & 3) << 4))];
            }
#pragma unroll
            for (int n = 0; n < 4; ++n) {
                const int R = wn * 64 + n * 16 + (lane & 15);
                b[n] = *(const long*)&Bs8[R * 64 + (krow ^ (((R >> 1) & 3) << 4))];
            }
#pragma unroll
            for (int m = 0; m < 4; ++m)
#pragma unroll
                for (int n = 0; n < 4; ++n)
                    acc[m][n] = __builtin_amdgcn_mfma_f32_16x16x32_fp8_fp8(a[m], b[n], acc[m][n], 0, 0, 0);
        }
        __syncthreads();                                 // drains vm+lgkm: next buffer ready
        cur ^= 1;
    }
#undef STAGE

    // pre-pack keys once; C/D layout: col=lane&15, row=(lane>>4)*4+j
    unsigned short kk4[4][4][4];
#pragma unroll
    for (int m = 0; m < 4; ++m)
#pragma unroll
        for (int n = 0; n < 4; ++n)
#pragma unroll
            for (int j = 0; j < 4; ++j)
                kk4[m][n][j] = (unsigned short)negkey(f2bf(acc[m][n][j]));

    unsigned short* Cs = (unsigned short*)smemB;         // Cs[64][136] = 17408 B, aliases staging
    const int fc = (lane & 15);
    const int fr = (lane >> 4) << 2;

    // ---- direct (row-major) writes: two 64-row half passes ----
#pragma unroll
    for (int h = 0; h < 2; ++h) {
        if (wm == h) {
#pragma unroll
            for (int m = 0; m < 4; ++m)
#pragma unroll
                for (int n = 0; n < 4; ++n) {
                    const int c = wn * 64 + n * 16 + fc;
                    const int rl = m * 16 + fr;          // local row 0..63
#pragma unroll
                    for (int j = 0; j < 4; ++j)
                        Cs[(rl + j) * 136 + c] = kk4[m][n][j];
                }
        }
        __syncthreads();
#pragma unroll
        for (int k = 0; k < 4; ++k) {
            const int lin = tid + k * 256;               // 0..1023
            const int rl = lin >> 4;                     // 0..63
            const int c0 = (lin & 15) * 8;
            i32x4 v = *(const i32x4*)&Cs[rl * 136 + c0];
            __builtin_nontemporal_store(v,
                (i32x4*)&simk[(size_t)(gr - rowBase + h * 64 + rl) * B_N + gc + c0]);
        }
        __syncthreads();
    }

    if (symmetric && tJ > tI) {
        // ---- transposed writes: two 64-col half passes (col-major bounce) ----
#pragma unroll
        for (int h = 0; h < 2; ++h) {
            if (wn == h) {
#pragma unroll
                for (int m = 0; m < 4; ++m)
#pragma unroll
                    for (int n = 0; n < 4; ++n) {
                        const int cl = n * 16 + fc;      // local col 0..63
                        const int r0 = wm * 64 + m * 16 + fr;
                        ushort4 pk;
                        pk.x = kk4[m][n][0]; pk.y = kk4[m][n][1];
                        pk.z = kk4[m][n][2]; pk.w = kk4[m][n][3];
                        *(ushort4*)&Cs[cl * 136 + r0] = pk;
                    }
            }
            __syncthreads();
#pragma unroll
            for (int k = 0; k < 4; ++k) {
                const int lin = tid + k * 256;           // 0..1023
                const int cl = lin >> 4;                 // 0..63
                const int r0 = (lin & 15) * 8;
                i32x4 v = *(const i32x4*)&Cs[cl * 136 + r0];
                __builtin_nontemporal_store(v,
                    (i32x4*)&simk[(size_t)(gc + h * 64 + cl) * B_N + gr + r0]);
            }
            __syncthreads();
        }
    }
}

// ---- block-per-row selection + loss: candidate compaction above TGKEY, exact bisect ----
__global__ __launch_bounds__(256) void select_loss(const unsigned short* __restrict__ simk,
                                                   const unsigned char* __restrict__ tgb,
                                                   const unsigned int* __restrict__ cm2,
                                                   const unsigned short* __restrict__ clist,
                                                   const int* __restrict__ off,
                                                   float* __restrict__ out, int rowBase) {
    __shared__ int nlist[256];
    __shared__ float s_partial[4];
    __shared__ int nln, s_cnt;

    const int tid = threadIdx.x;
    const int wid = tid >> 6, lane = tid & 63;
    const int row = rowBase + blockIdx.x;
    const unsigned short* srow = simk + (size_t)blockIdx.x * B_N;
    const int ti = tgb[row];
    const int o0 = off[ti], o1 = off[ti + 1];

    // load 32 keys, mask same-class halves to 0 (key 0 < TGKEY: never a candidate)
    int4 A[4];
    const unsigned m = cm2[ti * 256 + tid];
#pragma unroll
    for (int q = 0; q < 4; ++q) {
        A[q] = *(const int4*)(srow + q * 2048 + tid * 8);
#pragma unroll
        for (int d = 0; d < 4; ++d) {
            unsigned two = (m >> (q * 8 + d * 2)) & 3u;
            unsigned kill = ((two & 1u) * 0xFFFFu) | (((two >> 1) & 1u) * 0xFFFF0000u);
            int v = (d == 0 ? A[q].x : d == 1 ? A[q].y : d == 2 ? A[q].z : A[q].w);
            v = (int)((unsigned)v & ~kill);
            if (d == 0) A[q].x = v; else if (d == 1) A[q].y = v;
            else if (d == 2) A[q].z = v; else A[q].w = v;
        }
    }
    if (tid == 0) { nln = 0; s_cnt = 0; }
    __syncthreads();                                             // B1

#define ELEM_LOOP(BODY)                                                          \
    _Pragma("unroll")                                                            \
    for (int q = 0; q < 4; ++q) {                                                \
        _Pragma("unroll")                                                        \
        for (int d = 0; d < 4; ++d) {                                            \
            unsigned w32 = (unsigned)(d == 0 ? A[q].x : d == 1 ? A[q].y          \
                                    : d == 2 ? A[q].z : A[q].w);                 \
            _Pragma("unroll")                                                    \
            for (int h2 = 0; h2 < 2; ++h2) {                                     \
                unsigned key = h2 ? (w32 >> 16) : (w32 & 0xFFFFu);               \
                BODY                                                             \
            }                                                                    \
        }                                                                        \
    }

    // single scan: compact candidates above the conservative pre-threshold
    ELEM_LOOP(
        if (key > TGKEY) { int p = atomicAdd(&nln, 1); if (p < 256) nlist[p] = (int)key; }
    )
    __syncthreads();                                             // B2
    const int NC = nln;

    unsigned thr;
    int kremf;
    float S;

    if (NC >= 64 && NC <= 256) {
        // -------- fast path: wave0 solo; waves 1-3 exit now --------
        if (wid != 0) return;
        unsigned pk[8];
#pragma unroll
        for (int s2 = 0; s2 < 8; ++s2) {
            int idx = o0 + lane + s2 * 64;
            pk[s2] = (idx < o1)
                ? ((((unsigned)srow[clist[idx]]) << 9) | ((unsigned)lane << 3) | (unsigned)s2)
                : 0xFFFFFFFFu;
        }
        int4 cw = *(const int4*)&nlist[lane * 4];
        unsigned cand[4] = {(unsigned)cw.x, (unsigned)cw.y, (unsigned)cw.z, (unsigned)cw.w};
#pragma unroll
        for (int j = 0; j < 4; ++j)
            if (lane * 4 + j >= NC) cand[j] = 0;
        unsigned cur = 0;
#pragma unroll
        for (int bit = 15; bit >= 0; --bit) {
            unsigned trial = cur | (1u << bit);
            int c = (cand[0] >= trial) + (cand[1] >= trial) +
                    (cand[2] >= trial) + (cand[3] >= trial);
#pragma unroll
            for (int o = 1; o < 64; o <<= 1) c += __shfl_xor(c, o);
            if (c >= 64) cur = trial;
        }
        int r = (cand[0] > cur) + (cand[1] > cur) + (cand[2] > cur) + (cand[3] > cur);
#pragma unroll
        for (int o = 1; o < 64; o <<= 1) r += __shfl_xor(r, o);
        kremf = 64 - r;
        float f = 0.f;
#pragma unroll
        for (int j = 0; j < 4; ++j)
            if (cand[j] > cur) f += __expf(2.0f * bf2f(unkey(cand[j])));
#pragma unroll
        for (int o = 1; o < 64; o <<= 1) f += __shfl_xor(f, o);
        S = f;
        thr = cur;

        S += (float)kremf * __expf(2.0f * bf2f(unkey(thr)));
        float acc = 0.f;
#pragma unroll
        for (int rd = 0; rd < 8; ++rd) {
            unsigned best = pk[0];
#pragma unroll
            for (int s2 = 1; s2 < 8; ++s2) best = best < pk[s2] ? best : pk[s2];
#pragma unroll
            for (int o = 1; o < 64; o <<= 1) {
                unsigned v = (unsigned)__shfl_xor((int)best, o);
                best = best < v ? best : v;
            }
            if (best != 0xFFFFFFFFu) {
                if (lane == (int)((best >> 3) & 63u)) pk[best & 7u] = 0xFFFFFFFFu;
                if (lane == 0) {
                    float p = bf2f(unkey(best >> 9));
                    acc += logf(__expf(2.0f * p) + S) - 2.0f * p;
                }
            }
        }
        if (lane == 0) out[row] = acc * 0.125f;
    } else {
        // -------- exact fallback (distribution-independent): block-wide bisection --------
        unsigned cur = 0;
        for (int bit = 15; bit >= 0; --bit) {
            unsigned trial = cur | (1u << bit);
            int c = 0;
            ELEM_LOOP( c += (key >= trial) ? 1 : 0; )
#pragma unroll
            for (int o = 1; o < 64; o <<= 1) c += __shfl_xor(c, o);
            if (lane == 0) atomicAdd(&s_cnt, c);
            __syncthreads();
            int tot = s_cnt;
            __syncthreads();
            if (tid == 0) s_cnt = 0;
            __syncthreads();
            if (tot >= 64) cur = trial;
        }
        {
            int c = 0;
            ELEM_LOOP( c += (key > cur) ? 1 : 0; )
#pragma unroll
            for (int o = 1; o < 64; o <<= 1) c += __shfl_xor(c, o);
            if (lane == 0) atomicAdd(&s_cnt, c);
            __syncthreads();
        }
        const int r = s_cnt;
        kremf = 64 - r;
        {
            float f = 0.f;
            ELEM_LOOP( if (key > cur) f += __expf(2.0f * bf2f(unkey(key))); )
#pragma unroll
            for (int o = 1; o < 64; o <<= 1) f += __shfl_xor(f, o);
            if (lane == 0) s_partial[wid] = f;
            __syncthreads();
        }
        if (wid != 0) return;
        S = s_partial[0] + s_partial[1] + s_partial[2] + s_partial[3];
        thr = cur;

        unsigned pk[8];
#pragma unroll
        for (int s2 = 0; s2 < 8; ++s2) {
            int idx = o0 + lane + s2 * 64;
            pk[s2] = (idx < o1)
                ? ((((unsigned)srow[clist[idx]]) << 9) | ((unsigned)lane << 3) | (unsigned)s2)
                : 0xFFFFFFFFu;
        }
        S += (float)kremf * __expf(2.0f * bf2f(unkey(thr)));
        float acc = 0.f;
#pragma unroll
        for (int rd = 0; rd < 8; ++rd) {
            unsigned best = pk[0];
#pragma unroll
            for (int s2 = 1; s2 < 8; ++s2) best = best < pk[s2] ? best : pk[s2];
#pragma unroll
            for (int o = 1; o < 64; o <<= 1) {
                unsigned v = (unsigned)__shfl_xor((int)best, o);
                best = best < v ? best : v;
            }
            if (best != 0xFFFFFFFFu) {
                if (lane == (int)((best >> 3) & 63u)) pk[best & 7u] = 0xFFFFFFFFu;
                if (lane == 0) {
                    float p = bf2f(unkey(best >> 9));
                    acc += logf(__expf(2.0f * p) + S) - 2.0f * p;
                }
            }
        }
        if (lane == 0) out[row] = acc * 0.125f;
    }
#undef ELEM_LOOP
}

extern "C" void kernel_launch(void* const* d_in, const int* in_sizes, int n_in,
                              void* d_out, int out_size, void* d_ws, size_t ws_size,
                              hipStream_t stream) {
    const float* newf = (const float*)d_in[1];
    const unsigned int* tgtw = (const unsigned int*)d_in[2];
    float* out = (float*)d_out;
    char* ws = (char*)d_ws;
    unsigned char* tgb = (unsigned char*)ws;                          // 8 KB
    unsigned int* cm2 = (unsigned int*)(ws + 8192);                   // 100 KB
    int* off = (int*)(ws + 110592);                                   // 1 KB (129 ints)
    unsigned short* clist = (unsigned short*)(ws + 111616);           // 16 KB
    unsigned char* nf8 = (unsigned char*)(ws + 131072);               // 4 MB fp8 (aligned)
    unsigned short* simk = (unsigned short*)(ws + 131072 + ((size_t)4 << 20));

    size_t fixed = 131072 + ((size_t)4 << 20);
    size_t avail = (ws_size > fixed) ? (ws_size - fixed) : 0;
    long maxRows = (long)(avail / ((size_t)B_N * 2));
    int chunk = (int)((maxRows / 128) * 128);
    if (chunk < 128) chunk = 128;
    if (chunk > B_N) chunk = B_N;

    hipLaunchKernelGGL(prep_all, dim3(1), dim3(256), 0, stream, tgtw, tgb, clist, off);
    hipLaunchKernelGGL(class_masks, dim3(100), dim3(256), 0, stream, tgb, cm2);
    hipLaunchKernelGGL(normalize_k, dim3(B_N / 4), dim3(256), 0, stream, newf, nf8);
    if (chunk == B_N) {
        hipLaunchKernelGGL(gemm_sim, dim3(NTRI), dim3(256), 0, stream, nf8, simk, 0, 1);
        hipLaunchKernelGGL(select_loss, dim3(B_N), dim3(256), 0, stream,
                           simk, tgb, cm2, clist, off, out, 0);
    } else {
        for (int r0 = 0; r0 < B_N; r0 += chunk) {
            int rows = (B_N - r0 < chunk) ? (B_N - r0) : chunk;
            hipLaunchKernelGGL(gemm_sim, dim3(NT, rows / 128), dim3(256), 0, stream,
                               nf8, simk, r0, 0);
            hipLaunchKernelGGL(select_loss, dim3(rows), dim3(256), 0, stream,
                               simk, tgb, cm2, clist, off, out, r0);
        }
    }
}